// Round 9
// baseline (105.885 us; speedup 1.0000x reference)
//
#include <hip/hip_runtime.h>
#include <math.h>

#define NQ 512
#define NC 8000
#define DNUM 6
#define NBINS 50
#define DCAT 20
#define DENC 26      // DNUM + DCAT
#define DOUT 10
#define CHUNK 1000
#define NCHUNK 8

// ---------- encode ----------
// G_f(v) = sum_j ceil((v - u_fj*delta_fj)/delta_fj). Each per-bin map is
// fp-monotone in v (sub, div-by-positive, ceil), so all 50 bin diffs for a
// feature share sign => sum_j |bin_j(x)-bin_j(c)| == |G_f(x)-G_f(c)| exactly
// (integer-valued floats, sums << 2^24). 320-dim L1 -> 26-dim L1.
__global__ void encode(const float* __restrict__ c_num, const float* __restrict__ c_cat,
                       const float* __restrict__ x_num, const float* __restrict__ x_cat,
                       const float* __restrict__ delta, const float* __restrict__ u,
                       float* __restrict__ cEnc, float* __restrict__ qEnc) {
    int i = blockIdx.x * 256 + threadIdx.x;
    const int nA = (NC + NQ) * DNUM;          // 51072
    const int nB = (NC + NQ) * DCAT;          // 170240
    if (i < nA) {
        int f = i % DNUM, p = i / DNUM;
        bool is_c = p < NC;
        int idx = is_c ? p : p - NC;
        float v = (is_c ? c_num : x_num)[idx * DNUM + f];
        float g = 0.f;
        for (int j = 0; j < NBINS; ++j) {
            // exact reference op order: scaled_u = u*delta; ceil((v - scaled_u)/delta)
            float dl = delta[f * NBINS + j];
            float sc = u[f * NBINS + j] * dl;
            g += ceilf((v - sc) / dl);
        }
        if (is_c) cEnc[f * NC + idx] = g;
        else      qEnc[f * NQ + idx] = g;
    } else if (i < nA + nB) {
        int i2 = i - nA;
        int k = i2 % DCAT, p = i2 / DCAT;
        bool is_c = p < NC;
        int idx = is_c ? p : p - NC;
        float v = (is_c ? c_cat : x_cat)[idx * DCAT + k];
        if (is_c) cEnc[(DNUM + k) * NC + idx] = v;
        else      qEnc[(DNUM + k) * NQ + idx] = v;
    }
}

// ---------- all-in-one: block = 2 queries x all 8000 candidates ----------
// grid 256 blocks x 512 thr (1/CU). 500 active threads x 2 candidates per
// chunk. Per-chunk wave-local (m_w, s_w) lse partials -> no in-loop barrier;
// exact cross-wave combine at the end: M=min m_w, S=sum exp(M-m_w)*s_w.
// Class sums via predicated register reduction. No atomics, no global
// scratch, no finalize kernel. Output written directly.
__global__ __launch_bounds__(512) void nca_all(
    const float* __restrict__ cEnc, const float* __restrict__ qEnc,
    const int* __restrict__ cy, float* __restrict__ out) {
    __shared__ float xs[DENC * 2];              // 52: xs[d*2+q]
    __shared__ float parts[NCHUNK * 8 * 24];    // [chunk][wave][q*12+slot], 6 KB
    __shared__ float tmp[2][NCHUNK];
    __shared__ float lse_sh[2];

    const int tid = threadIdx.x;
    const int q0 = blockIdx.x * 2;
    if (tid < DENC * 2) {
        int d = tid >> 1, q = tid & 1;
        xs[tid] = qEnc[d * NQ + q0 + q];
    }
    __syncthreads();

    const bool act = tid < 500;                 // 500 * 2 = 1000 candidates
    const int cl = act ? 2 * tid : 996;         // clamp inactive to safe addr
    const int lane = tid & 63, wave = tid >> 6;

    for (int chunk = 0; chunk < NCHUNK; ++chunk) {
        const float* cp = cEnc + chunk * CHUNK + cl;
        // preload all 26 dims -> 26 independent in-flight loads
        float2 cv[DENC];
#pragma unroll
        for (int d = 0; d < DENC; ++d) cv[d] = *(const float2*)(cp + (size_t)d * NC);

        float a00 = 0.f, a01 = 0.f, a10 = 0.f, a11 = 0.f;   // a[q][cand]
#pragma unroll
        for (int d = 0; d < DENC; ++d) {
            float x0 = xs[2 * d], x1 = xs[2 * d + 1];
            a00 += fabsf(cv[d].x - x0); a01 += fabsf(cv[d].y - x0);
            a10 += fabsf(cv[d].x - x1); a11 += fabsf(cv[d].y - x1);
        }

        // wave-local min per q
        float m0 = act ? fminf(a00, a01) : INFINITY;
        float m1 = act ? fminf(a10, a11) : INFINITY;
#pragma unroll
        for (int sh = 32; sh >= 1; sh >>= 1) {
            m0 = fminf(m0, __shfl_xor(m0, sh));
            m1 = fminf(m1, __shfl_xor(m1, sh));
        }

        int2 y = *(const int2*)(cy + chunk * CHUNK + cl);
        float e00 = 0.f, e01 = 0.f, e10 = 0.f, e11 = 0.f, s0 = 0.f, s1 = 0.f;
        if (act) {
            e00 = __expf(-a00); e01 = __expf(-a01);
            e10 = __expf(-a10); e11 = __expf(-a11);
            s0 = __expf(m0 - a00) + __expf(m0 - a01);
            s1 = __expf(m1 - a10) + __expf(m1 - a11);
        }

        // r[0..9] q0 class sums, r[10] = s0, r[11..20] q1 class, r[21] = s1
        float r[22];
#pragma unroll
        for (int k = 0; k < DOUT; ++k) {
            r[k]      = (y.x == k ? e00 : 0.f) + (y.y == k ? e01 : 0.f);
            r[11 + k] = (y.x == k ? e10 : 0.f) + (y.y == k ? e11 : 0.f);
        }
        r[10] = s0; r[21] = s1;
#pragma unroll
        for (int k = 0; k < 22; ++k) {
#pragma unroll
            for (int sh = 32; sh >= 1; sh >>= 1) r[k] += __shfl_xor(r[k], sh);
        }
        if (lane == 0) {
            float* p = parts + chunk * 192 + wave * 24;
            p[0] = m0; p[1] = r[10];
#pragma unroll
            for (int k = 0; k < DOUT; ++k) p[2 + k] = r[k];
            p[12] = m1; p[13] = r[21];
#pragma unroll
            for (int k = 0; k < DOUT; ++k) p[14 + k] = r[11 + k];
        }
    }
    __syncthreads();

    // per-(q,chunk) lse: combine 8 wave partials exactly
    if (tid < 16) {
        int q = tid & 1, ch = tid >> 1;
        const float* p = parts + ch * 192 + q * 12;
        float M = INFINITY;
#pragma unroll
        for (int w = 0; w < 8; ++w) M = fminf(M, p[w * 24]);
        float S = 0.f;
#pragma unroll
        for (int w = 0; w < 8; ++w) S += __expf(M - p[w * 24]) * p[w * 24 + 1];
        tmp[q][ch] = logf(S) - M;     // log(sum_c exp(-d)) for this chunk
    }
    __syncthreads();
    if (tid < 2) {
        float l = 0.f;
#pragma unroll
        for (int ch = 0; ch < NCHUNK; ++ch) l += tmp[tid][ch];
        lse_sh[tid] = l;
    }
    __syncthreads();
    if (tid < 2 * DOUT) {
        int q = tid / DOUT, k = tid % DOUT;
        float s = 0.f;
#pragma unroll
        for (int ch = 0; ch < NCHUNK; ++ch) {
            const float* p = parts + ch * 192 + q * 12 + 2 + k;
#pragma unroll
            for (int w = 0; w < 8; ++w) s += p[w * 24];
        }
        out[(q0 + q) * DOUT + k] = logf(s + 1e-8f) - lse_sh[q];
    }
}

extern "C" void kernel_launch(void* const* d_in, const int* in_sizes, int n_in,
                              void* d_out, int out_size, void* d_ws, size_t ws_size,
                              hipStream_t stream) {
    const float* x_num = (const float*)d_in[0];
    const float* x_cat = (const float*)d_in[1];
    const float* c_num = (const float*)d_in[2];
    const float* c_cat = (const float*)d_in[3];
    const int*   c_y   = (const int*)d_in[4];
    const float* delta = (const float*)d_in[5];
    const float* u     = (const float*)d_in[6];

    float* ws = (float*)d_ws;
    float* cEnc = ws;                             // 26*8000 = 208,000 floats
    float* qEnc = cEnc + (size_t)DENC * NC;       // 26*512  = 13,312

    const int total = (NC + NQ) * DENC;           // 221,312
    encode<<<(total + 255) / 256, 256, 0, stream>>>(
        c_num, c_cat, x_num, x_cat, delta, u, cEnc, qEnc);
    nca_all<<<NQ / 2, 512, 0, stream>>>(cEnc, qEnc, c_y, (float*)d_out);
}

// Round 10
// 92.369 us; speedup vs baseline: 1.1463x; 1.1463x over previous
//
#include <hip/hip_runtime.h>
#include <math.h>

#define NQ 512
#define NC 8000
#define DNUM 6
#define NBINS 50
#define DCAT 20
#define DENC 26      // DNUM + DCAT
#define DOUT 10
#define CHUNK 1000
#define NCHUNK 8

// ---------- encode ----------
// G_f(v) = sum_j ceil((v - u_fj*delta_fj)/delta_fj). Each per-bin map is
// fp-monotone in v (sub, div-by-positive, ceil), so all 50 bin diffs for a
// feature share sign => sum_j |bin_j(x)-bin_j(c)| == |G_f(x)-G_f(c)| exactly
// (integer-valued floats, sums << 2^24). 320-dim L1 -> 26-dim L1.
__global__ void encode(const float* __restrict__ c_num, const float* __restrict__ c_cat,
                       const float* __restrict__ x_num, const float* __restrict__ x_cat,
                       const float* __restrict__ delta, const float* __restrict__ u,
                       float* __restrict__ cEnc, float* __restrict__ qEnc) {
    int i = blockIdx.x * 256 + threadIdx.x;
    const int nA = (NC + NQ) * DNUM;          // 51072
    const int nB = (NC + NQ) * DCAT;          // 170240
    if (i < nA) {
        int f = i % DNUM, p = i / DNUM;
        bool is_c = p < NC;
        int idx = is_c ? p : p - NC;
        float v = (is_c ? c_num : x_num)[idx * DNUM + f];
        float g = 0.f;
        for (int j = 0; j < NBINS; ++j) {
            // exact reference op order: scaled_u = u*delta; ceil((v - scaled_u)/delta)
            float dl = delta[f * NBINS + j];
            float sc = u[f * NBINS + j] * dl;
            g += ceilf((v - sc) / dl);
        }
        if (is_c) cEnc[f * NC + idx] = g;
        else      qEnc[f * NQ + idx] = g;
    } else if (i < nA + nB) {
        int i2 = i - nA;
        int k = i2 % DCAT, p = i2 / DCAT;
        bool is_c = p < NC;
        int idx = is_c ? p : p - NC;
        float v = (is_c ? c_cat : x_cat)[idx * DCAT + k];
        if (is_c) cEnc[(DNUM + k) * NC + idx] = v;
        else      qEnc[(DNUM + k) * NQ + idx] = v;
    }
}

// ---------- all-in-one: block = 2 queries x all 8000 candidates ----------
// grid 256 x 512 (1 block/CU). vs R9: class sums accumulate per-thread in
// registers across ALL chunks (one end-of-kernel butterfly, 120 DS-ops,
// instead of 8x960); chunk loop keeps only the 4 lse chains (24 DS-ops per
// chunk); query values live in registers (no in-loop LDS reads).
__global__ __launch_bounds__(512) void nca_all(
    const float* __restrict__ cEnc, const float* __restrict__ qEnc,
    const int* __restrict__ cy, float* __restrict__ out) {
    __shared__ float xs[DENC * 2];              // 52
    __shared__ float ms_parts[NCHUNK * 8 * 4];  // [chunk][wave][m0,s0,m1,s1]
    __shared__ float cls_parts[8][2 * DOUT];    // [wave][q*10+k]
    __shared__ float tmp[2][NCHUNK];
    __shared__ float lse_sh[2];

    const int tid = threadIdx.x;
    const int q0 = blockIdx.x * 2;
    if (tid < DENC * 2) {
        int d = tid >> 1, q = tid & 1;
        xs[tid] = qEnc[d * NQ + q0 + q];
    }
    __syncthreads();

    // queries -> registers (kills in-loop LDS reads)
    float xr0[DENC], xr1[DENC];
#pragma unroll
    for (int d = 0; d < DENC; ++d) { xr0[d] = xs[2 * d]; xr1[d] = xs[2 * d + 1]; }

    const bool act = tid < 500;                 // 500 * 2 = 1000 candidates
    const int cl = act ? 2 * tid : 996;         // clamp inactive to safe addr
    const int lane = tid & 63, wave = tid >> 6;

    float cls[2 * DOUT];                        // per-thread class sums, all chunks
#pragma unroll
    for (int k = 0; k < 2 * DOUT; ++k) cls[k] = 0.f;

    for (int chunk = 0; chunk < NCHUNK; ++chunk) {
        const float* cp = cEnc + chunk * CHUNK + cl;
        float2 cv[DENC];
#pragma unroll
        for (int d = 0; d < DENC; ++d) cv[d] = *(const float2*)(cp + (size_t)d * NC);

        float a00 = 0.f, a01 = 0.f, a10 = 0.f, a11 = 0.f;   // a[q][cand]
#pragma unroll
        for (int d = 0; d < DENC; ++d) {
            a00 += fabsf(cv[d].x - xr0[d]); a01 += fabsf(cv[d].y - xr0[d]);
            a10 += fabsf(cv[d].x - xr1[d]); a11 += fabsf(cv[d].y - xr1[d]);
        }

        // wave-local min per q (lse partial)
        float m0 = act ? fminf(a00, a01) : INFINITY;
        float m1 = act ? fminf(a10, a11) : INFINITY;
#pragma unroll
        for (int sh = 32; sh >= 1; sh >>= 1) {
            m0 = fminf(m0, __shfl_xor(m0, sh));
            m1 = fminf(m1, __shfl_xor(m1, sh));
        }

        int2 y = *(const int2*)(cy + chunk * CHUNK + cl);
        float s0 = 0.f, s1 = 0.f;
        if (act) {
            float e00 = __expf(-a00), e01 = __expf(-a01);
            float e10 = __expf(-a10), e11 = __expf(-a11);
            s0 = __expf(m0 - a00) + __expf(m0 - a01);
            s1 = __expf(m1 - a10) + __expf(m1 - a11);
            // class sums accumulate in registers across chunks
#pragma unroll
            for (int k = 0; k < DOUT; ++k) {
                cls[k]        += (y.x == k ? e00 : 0.f) + (y.y == k ? e01 : 0.f);
                cls[DOUT + k] += (y.x == k ? e10 : 0.f) + (y.y == k ? e11 : 0.f);
            }
        }
#pragma unroll
        for (int sh = 32; sh >= 1; sh >>= 1) {
            s0 += __shfl_xor(s0, sh);
            s1 += __shfl_xor(s1, sh);
        }
        if (lane == 0) {
            float* p = ms_parts + (chunk * 8 + wave) * 4;
            p[0] = m0; p[1] = s0; p[2] = m1; p[3] = s1;
        }
    }

    // one butterfly for the 20 class sums
#pragma unroll
    for (int k = 0; k < 2 * DOUT; ++k) {
#pragma unroll
        for (int sh = 32; sh >= 1; sh >>= 1) cls[k] += __shfl_xor(cls[k], sh);
    }
    if (lane == 0) {
#pragma unroll
        for (int k = 0; k < 2 * DOUT; ++k) cls_parts[wave][k] = cls[k];
    }
    __syncthreads();

    // per-(q,chunk) lse: combine 8 wave partials exactly
    if (tid < 16) {
        int q = tid & 1, ch = tid >> 1;
        const float* p = ms_parts + ch * 32 + 2 * q;
        float M = INFINITY;
#pragma unroll
        for (int w = 0; w < 8; ++w) M = fminf(M, p[w * 4]);
        float S = 0.f;
#pragma unroll
        for (int w = 0; w < 8; ++w) S += __expf(M - p[w * 4]) * p[w * 4 + 1];
        tmp[q][ch] = logf(S) - M;     // log(sum_c exp(-d)) for this chunk
    }
    __syncthreads();
    if (tid < 2) {
        float l = 0.f;
#pragma unroll
        for (int ch = 0; ch < NCHUNK; ++ch) l += tmp[tid][ch];
        lse_sh[tid] = l;
    }
    __syncthreads();
    if (tid < 2 * DOUT) {
        int q = tid / DOUT, k = tid % DOUT;
        float s = 0.f;
#pragma unroll
        for (int w = 0; w < 8; ++w) s += cls_parts[w][q * DOUT + k];
        out[(q0 + q) * DOUT + k] = logf(s + 1e-8f) - lse_sh[q];
    }
}

extern "C" void kernel_launch(void* const* d_in, const int* in_sizes, int n_in,
                              void* d_out, int out_size, void* d_ws, size_t ws_size,
                              hipStream_t stream) {
    const float* x_num = (const float*)d_in[0];
    const float* x_cat = (const float*)d_in[1];
    const float* c_num = (const float*)d_in[2];
    const float* c_cat = (const float*)d_in[3];
    const int*   c_y   = (const int*)d_in[4];
    const float* delta = (const float*)d_in[5];
    const float* u     = (const float*)d_in[6];

    float* ws = (float*)d_ws;
    float* cEnc = ws;                             // 26*8000 = 208,000 floats
    float* qEnc = cEnc + (size_t)DENC * NC;       // 26*512  = 13,312

    const int total = (NC + NQ) * DENC;           // 221,312
    encode<<<(total + 255) / 256, 256, 0, stream>>>(
        c_num, c_cat, x_num, x_cat, delta, u, cEnc, qEnc);
    nca_all<<<NQ / 2, 512, 0, stream>>>(cEnc, qEnc, c_y, (float*)d_out);
}